// Round 16
// baseline (210.189 us; speedup 1.0000x reference)
//
#include <hip/hip_runtime.h>
#include <hip/hip_bf16.h>
#include <math.h>

// Problem sizes
#define B_SZ 16
#define L_SZ 2048
#define H_SZ 1024
#define M_TOT (B_SZ * L_SZ)   // 32768 rows
#define N_TOT H_SZ            // 1024 outputs
#define KD (2 * H_SZ)         // 2048 concat K (key | query)
#define LC 16
#define LCHUNK (L_SZ / LC)    // 128

// GEMM geometry (256^2 template, merged 4-phase)
#define BM2 256
#define BN2 256
#define BK2 64
#define NT2 (KD / BK2)        // 32 K-tiles
#define NBN2 (N_TOT / BN2)    // 4 col blocks
#define NBM2 (M_TOT / BM2)    // 128 row blocks

typedef short short8 __attribute__((ext_vector_type(8)));
typedef float f32x4 __attribute__((ext_vector_type(4)));

#define GL16(gp, lp)                                                        \
    __builtin_amdgcn_global_load_lds(                                       \
        (const __attribute__((address_space(1))) unsigned int*)(gp),        \
        (__attribute__((address_space(3))) unsigned int*)(lp), 16, 0, 0)

#define BARRIER() __builtin_amdgcn_s_barrier()
#define SCHEDB()  __builtin_amdgcn_sched_barrier(0)
#define LGKM0()   asm volatile("s_waitcnt lgkmcnt(0)" ::: "memory")
#define VMCNT4()  asm volatile("s_waitcnt vmcnt(4)" ::: "memory")
#define VMCNT10() asm volatile("s_waitcnt vmcnt(10)" ::: "memory")
#define VMCNT0()  asm volatile("s_waitcnt vmcnt(0)" ::: "memory")

// HW packed f32->bf16 (RNE), 1 inst / 2 elems (T12 recipe).
static __device__ __forceinline__ short8 pack8(float4 x, float4 y) {
    unsigned w0, w1, w2, w3;
    asm("v_cvt_pk_bf16_f32 %0, %1, %2" : "=v"(w0) : "v"(x.x), "v"(x.y));
    asm("v_cvt_pk_bf16_f32 %0, %1, %2" : "=v"(w1) : "v"(x.z), "v"(x.w));
    asm("v_cvt_pk_bf16_f32 %0, %1, %2" : "=v"(w2) : "v"(y.x), "v"(y.y));
    asm("v_cvt_pk_bf16_f32 %0, %1, %2" : "=v"(w3) : "v"(y.z), "v"(y.w));
    int4 q{(int)w0, (int)w1, (int)w2, (int)w3};
    return __builtin_bit_cast(short8, q);
}

// tanh(x) = 1 - 2/(e^{2x}+1); ~1e-6 abs err, exact saturation.
static __device__ __forceinline__ float fast_tanh(float x) {
    float e = __expf(2.0f * x);
    return 1.0f - 2.0f * __builtin_amdgcn_rcpf(e + 1.0f);
}

// ---------------------------------------------------------------------------
// Kernel 1: weight concat + fp32->bf16 only (4 MB): Wb[o] = [Wk[o] | Wq[o]]
// ---------------------------------------------------------------------------
__global__ __launch_bounds__(256) void conv_w(
    const float* __restrict__ Wq, const float* __restrict__ Wk,
    unsigned short* __restrict__ Wb)
{
    int idx = blockIdx.x * 256 + threadIdx.x;
    int e0 = idx * 8;
    int o  = e0 >> 11;
    int kk = e0 & 2047;
    const float* src = (kk < H_SZ) ? (Wk + (size_t)o * H_SZ + kk)
                                   : (Wq + (size_t)o * H_SZ + (kk - H_SZ));
    float4 x = ((const float4*)src)[0];
    float4 y = ((const float4*)src)[1];
    *(short8*)(Wb + e0) = pack8(x, y);
}

// ---------------------------------------------------------------------------
// Kernel 2: 256x256x64 MERGED 4-phase score GEMM, fused fp32->bf16 A-staging.
//   vs R13 (8-phase): phase pairs merged -> 2 phases/tile, halving barriers
//   (8->4) and lgkm drains (4->2); MFMA burst 16->32 (bigger shadow for the
//   A-chain tail). Staging interleave preserved (m196 caveat).
//   Per tile u (buf = parity):
//    phA: 8x LDA(ks0) + 4x LDB(ks0) + STAGE_B(Kh1,u+1)->(1-buf) +
//         ALOAD(rA0,kh0,u+2); BAR; LGKM0; 32 MFMA;
//         SCHEDB; AWRITE(rA1 -> (1-buf).kh1); VMCNT10; BAR;
//    phB: 8x LDA(ks1) + 4x LDB(ks1) + STAGE_B(Kh0,u+2)->buf +
//         ALOAD(rA1,kh1,u+2); BAR; LGKM0; 32 MFMA;
//         SCHEDB; AWRITE(rA0 -> buf.kh0); VMCNT10; BAR;
//   VMCNT10 FIFO-exact: VMEM stream/phase = [2 B-gload][4 A-load]; the B
//   half consumed next phase has exactly 10 newer ops at its guard point
//   (e.g. B(u+1,kh1) at end-phB: 4 rA0 + 6 phB = 10 newer).
//   Publication: phase-tail ds_writes retire under next phase's LGKM0+BAR,
//   >=2 barriers before their consumer (A(u+1,kh1): written u.phA, consumed
//   u+1.phB). WAR: every overwritten region's last readers drained at their
//   phase's LGKM0, >=1 barrier before the write issue.
// ---------------------------------------------------------------------------
__global__ __launch_bounds__(512, 2) void score_gemm_4ph(
    const float* __restrict__ keyg,          // key_t  [M][1024] fp32 (k<1024)
    const float* __restrict__ qryg,          // query  [M][1024] fp32 (k>=1024)
    const unsigned short* __restrict__ Wb,   // [1024][2048] bf16
    const float* __restrict__ bias,
    const float* __restrict__ wscore,
    float* __restrict__ spart)               // [M][4]
{
    extern __shared__ char smem[];           // 128 KB dynamic
    char* Albase = smem;                     // A: 64 KB
    char* Blbase = smem + 65536;             // B: 64 KB

    const int t    = threadIdx.x;
    const int lane = t & 63;
    const int wid  = t >> 6;                 // 0..7
    const int wr   = wid >> 2;               // 0..1 (WARPS_M=2, 128 rows each)
    const int wc   = wid & 3;                // 0..3 (WARPS_N=4, 64 cols each)

    // XCD-aware remap: 512 blocks = 8 xcd * 16 bm * 4 bn (bn innermost)
    const int id  = blockIdx.x;
    const int xcd = id & 7;
    const int j   = id >> 3;                 // 0..63
    const int bn  = j & 3;
    const int bm  = xcd * 16 + (j >> 2);
    const int r0  = bm * BM2;
    const int c0  = bn * BN2;

    // ---- B staging per-lane global offsets (pre-swizzled source) ----
    const int srow = lane >> 2;
    const int scol = ((lane & 3) * 8) ^ ((lane >= 32) ? 16 : 0);
    const size_t gB0 = (size_t)(c0 + (wid)     * 16 + srow) * KD + scol;
    const size_t gB1 = (size_t)(c0 + (8 + wid) * 16 + srow) * KD + scol;

    // ---- frag ds_read addressing (swizzled) ----
    const int fr  = lane & 15;               // row within subtile / C-col
    const int fk8 = (lane >> 4) * 8;         // k-offset within 32-k step
    const int subbyte = (fr * 64 + fk8 * 2) ^ ((fr & 8) << 2);  // ^32 if fr>=8
    const char* aL = Albase + wr * 8192 + subbyte;   // + rsub*1024 immediates
    const char* bL = Blbase + wc * 4096 + subbyte;

    // A reg-staging addressing: thread covers subtiles {wid, 8+wid} of a
    // 256x32 K-half; per subtile: row 16s+(lane>>2), cols (lane&3)*8 .. +8.
    const int arow0 = r0 + wid * 16 + (lane >> 2);
    const int arow1 = r0 + (8 + wid) * 16 + (lane >> 2);
    const int acsub = (lane & 3) * 8;
    // swizzled ds_write target chunk within subtile
    const int awbyte = (lane * 16) ^ (lane & 32);

#define ALOAD(rr, khalf, kt_) do {                                           \
    int koff = (((kt_) & 31) * 64) + (khalf) * 32 + acsub;                   \
    const float* base_ = (koff < H_SZ) ? (keyg + koff)                       \
                                       : (qryg + (koff - H_SZ));             \
    const float* p0_ = base_ + (size_t)arow0 * H_SZ;                         \
    const float* p1_ = base_ + (size_t)arow1 * H_SZ;                         \
    rr[0] = ((const float4*)p0_)[0]; rr[1] = ((const float4*)p0_)[1];        \
    rr[2] = ((const float4*)p1_)[0]; rr[3] = ((const float4*)p1_)[1];        \
} while (0)
#define AWRITE(rr, buf, khalf) do {                                          \
    char* d_ = Albase + (((buf)*2 + (khalf))*16 + wid)*1024 + awbyte;        \
    *(short8*)d_            = pack8(rr[0], rr[1]);                           \
    *(short8*)(d_ + 8*1024) = pack8(rr[2], rr[3]);                           \
} while (0)
#define STAGE_B(buf, khalf, kt_) do {                                        \
    int kpos = (((kt_) & 31) * 64) + (khalf) * 32;                           \
    GL16(Wb + gB0 + kpos, Blbase + (((buf)*2 + (khalf))*16 + wid)*1024);     \
    GL16(Wb + gB1 + kpos, Blbase + (((buf)*2 + (khalf))*16 + 8 + wid)*1024); \
} while (0)

    float4 rA0[4], rA1[4];
    short8 a_f[8], b_f[4];
    f32x4 acc[8][4] = {};

#define LDA8(buf, ks) do { _Pragma("unroll")                                 \
    for (int m = 0; m < 8; ++m)                                              \
        a_f[m] = *(const short8*)(aL +                                       \
            (((buf)*2 + (ks))*16 + m) * 1024); } while (0)
#define LDB4(buf, ks) do { _Pragma("unroll")                                 \
    for (int n = 0; n < 4; ++n)                                              \
        b_f[n] = *(const short8*)(bL +                                       \
            (((buf)*2 + (ks))*16 + n) * 1024); } while (0)
#define MM32() do {                                                          \
    __builtin_amdgcn_s_setprio(1);                                           \
    _Pragma("unroll")                                                        \
    for (int mm = 0; mm < 8; ++mm) { _Pragma("unroll")                       \
        for (int n = 0; n < 4; ++n)                                          \
            acc[mm][n] = __builtin_amdgcn_mfma_f32_16x16x32_bf16(            \
                a_f[mm], b_f[n], acc[mm][n], 0, 0, 0); }                     \
    __builtin_amdgcn_s_setprio(0); } while (0)

#define TILE(buf, u) do {                                                    \
    LDA8(buf, 0); LDB4(buf, 0);                                              \
    STAGE_B(1-(buf), 1, (u)+1); ALOAD(rA0, 0, (u)+2);                        \
    BARRIER(); LGKM0(); MM32();                                              \
    SCHEDB(); AWRITE(rA1, 1-(buf), 1); VMCNT10(); BARRIER();                 \
    LDA8(buf, 1); LDB4(buf, 1);                                              \
    STAGE_B(buf, 0, (u)+2); ALOAD(rA1, 1, (u)+2);                            \
    BARRIER(); LGKM0(); MM32();                                              \
    SCHEDB(); AWRITE(rA0, buf, 0); VMCNT10(); BARRIER();                     \
} while (0)

    // ---- prologue (same invariant as R13): LDS gets T0 (A+B, both halves)
    //      + T1 Kh0 (A+B); rA1 left holding T1 Kh1 (in flight into loop).
    STAGE_B(0, 0, 0); STAGE_B(0, 1, 0); STAGE_B(1, 0, 1);
    ALOAD(rA0, 0, 0); ALOAD(rA1, 1, 0);
    AWRITE(rA0, 0, 0); AWRITE(rA1, 0, 1);    // compiler waits rA0/rA1
    ALOAD(rA0, 0, 1);  AWRITE(rA0, 1, 0);    // T1 Kh0
    ALOAD(rA1, 1, 1);                        // T1 Kh1 (4 newest VMEM)
    VMCNT4();                                // drain all but rA1's 4 loads
    LGKM0();                                 // publish prologue ds_writes
    BARRIER();

    // ---- main loop: 32 K-tiles, unrolled x2 for static buffer index ----
    for (int it = 0; it < NT2; it += 2) {
        TILE(0, it);
        TILE(1, it + 1);
    }

    // drain stray wrapped prefetches before reusing LDS
    VMCNT0();
    __syncthreads();

    // ---- fused epilogue: tanh + w_score partial over this col-tile ----
    float* part = (float*)smem;              // [4][256]
    const int fg = lane >> 4;
    float wsv[4], bsv[4];
    #pragma unroll
    for (int n = 0; n < 4; ++n) {
        int cg = c0 + wc * 64 + n * 16 + fr;
        wsv[n] = wscore[cg];
        bsv[n] = bias[cg];
    }
    #pragma unroll
    for (int mm = 0; mm < 8; ++mm) {
        #pragma unroll
        for (int r = 0; r < 4; ++r) {
            float s = 0.f;
            #pragma unroll
            for (int n = 0; n < 4; ++n)
                s += wsv[n] * fast_tanh(acc[mm][n][r] + bsv[n]);
            s += __shfl_xor(s, 1, 64);
            s += __shfl_xor(s, 2, 64);
            s += __shfl_xor(s, 4, 64);
            s += __shfl_xor(s, 8, 64);
            if (fr == 0)
                part[wc * 256 + wr * 128 + mm * 16 + fg * 4 + r] = s;
        }
    }
    __syncthreads();
    if (t < 256) {
        float v = part[t] + part[256 + t] + part[512 + t] + part[768 + t];
        spart[(size_t)(r0 + t) * 4 + bn] = v;
    }

#undef ALOAD
#undef AWRITE
#undef STAGE_B
#undef LDA8
#undef LDB4
#undef MM32
#undef TILE
}

// ---------------------------------------------------------------------------
// Kernel 3: per-batch softmax over L (sums the 4 partials in fixed order)
// ---------------------------------------------------------------------------
__global__ __launch_bounds__(256) void softmax_k(
    const float* __restrict__ spart,         // [M][4]
    float* __restrict__ attn)
{
    __shared__ float sc[L_SZ];
    __shared__ float red[8];
    const int b = blockIdx.x, t = threadIdx.x;
    const int lane = t & 63, wid = t >> 6;

    float lmax = -1e30f;
    #pragma unroll
    for (int i = 0; i < 8; ++i) {
        int l = t + i * 256;
        float4 u = *(const float4*)(spart + ((size_t)b * L_SZ + l) * 4);
        float s = (u.x + u.y) + (u.z + u.w);
        sc[l] = s;
        lmax = fmaxf(lmax, s);
    }
    #pragma unroll
    for (int off = 32; off; off >>= 1) lmax = fmaxf(lmax, __shfl_xor(lmax, off, 64));
    if (lane == 0) red[wid] = lmax;
    __syncthreads();
    float bmax = fmaxf(fmaxf(red[0], red[1]), fmaxf(red[2], red[3]));

    float lsum = 0.f;
    #pragma unroll
    for (int i = 0; i < 8; ++i) {
        int l = t + i * 256;
        float e = expf(sc[l] - bmax);
        sc[l] = e;
        lsum += e;
    }
    #pragma unroll
    for (int off = 32; off; off >>= 1) lsum += __shfl_xor(lsum, off, 64);
    if (lane == 0) red[4 + wid] = lsum;
    __syncthreads();
    float inv = 1.f / (((red[4] + red[5]) + (red[6] + red[7])));

    #pragma unroll
    for (int i = 0; i < 8; ++i) {
        int l = t + i * 256;
        attn[(size_t)b * L_SZ + l] = sc[l] * inv;
    }
}

// ---------------------------------------------------------------------------
// Kernel 4: context partials  cpart[b][lc][h] = sum_{l in chunk} attn*V
// ---------------------------------------------------------------------------
__global__ __launch_bounds__(256) void ctx_part_k(
    const float* __restrict__ attn, const float* __restrict__ value,
    float* __restrict__ cpart)
{
    const int bid = blockIdx.x;              // B*4*LC = 1024 blocks
    const int b   = bid >> 6;
    const int rem = bid & 63;
    const int hc  = rem >> 4;
    const int lc  = rem & 15;
    const int h   = hc * 256 + threadIdx.x;

    const float* ap = attn + (size_t)b * L_SZ + lc * LCHUNK;
    const float* vp = value + ((size_t)b * L_SZ + lc * LCHUNK) * H_SZ + h;
    float acc = 0.f;
    #pragma unroll 4
    for (int l = 0; l < LCHUNK; ++l)
        acc += ap[l] * vp[(size_t)l * H_SZ];
    cpart[((size_t)(b * LC + lc)) * H_SZ + h] = acc;
}

// ---------------------------------------------------------------------------
// Kernel 5: reduce context partials -> d_out[0:16384]
// ---------------------------------------------------------------------------
__global__ __launch_bounds__(256) void ctx_reduce_k(
    const float* __restrict__ cpart, float* __restrict__ ctx)
{
    const int idx = blockIdx.x * 256 + threadIdx.x;
    const int b = idx >> 10, h = idx & 1023;
    float s = 0.f;
    #pragma unroll
    for (int lc = 0; lc < LC; ++lc)
        s += cpart[((size_t)(b * LC + lc)) * H_SZ + h];
    ctx[idx] = s;
}

// ---------------------------------------------------------------------------
extern "C" void kernel_launch(void* const* d_in, const int* in_sizes, int n_in,
                              void* d_out, int out_size, void* d_ws, size_t ws_size,
                              hipStream_t stream) {
    const float* query  = (const float*)d_in[0];
    const float* key_t  = (const float*)d_in[1];
    const float* value  = (const float*)d_in[2];
    const float* Wq     = (const float*)d_in[3];
    const float* Wk     = (const float*)d_in[4];
    const float* bias   = (const float*)d_in[5];
    const float* wscore = (const float*)d_in[6];

    float* out      = (float*)d_out;
    float* ctx_out  = out;                    // [16][1024] context
    float* attn_out = out + B_SZ * H_SZ;      // [16][2048] attn

    char* ws = (char*)d_ws;
    unsigned short* Wb = (unsigned short*)ws;                        // 4 MB
    float* spart = (float*)(ws + 4ull * 1024 * 1024);                // 512 KB [M][4]
    float* cpart = (float*)(ws + 5ull * 1024 * 1024);                // 1 MB

    (void)hipFuncSetAttribute((const void*)score_gemm_4ph,
                              hipFuncAttributeMaxDynamicSharedMemorySize, 131072);

    conv_w<<<1024, 256, 0, stream>>>(Wq, Wk, Wb);

    score_gemm_4ph<<<NBM2 * NBN2, 512, 131072, stream>>>(
        key_t, query, Wb, bias, wscore, spart);

    softmax_k<<<B_SZ, 256, 0, stream>>>(spart, attn_out);
    ctx_part_k<<<B_SZ * 4 * LC, 256, 0, stream>>>(attn_out, value, cpart);
    ctx_reduce_k<<<(B_SZ * H_SZ) / 256, 256, 0, stream>>>(cpart, ctx_out);
}

// Round 17
// 204.431 us; speedup vs baseline: 1.0282x; 1.0282x over previous
//
#include <hip/hip_runtime.h>
#include <hip/hip_bf16.h>
#include <math.h>

// Problem sizes
#define B_SZ 16
#define L_SZ 2048
#define H_SZ 1024
#define M_TOT (B_SZ * L_SZ)   // 32768 rows
#define N_TOT H_SZ            // 1024 outputs
#define KD (2 * H_SZ)         // 2048 concat K (key | query)
#define LC 16
#define LCHUNK (L_SZ / LC)    // 128

// 8-phase GEMM geometry (256^2 template)
#define BM2 256
#define BN2 256
#define BK2 64
#define NT2 (KD / BK2)        // 32 K-tiles
#define NBN2 (N_TOT / BN2)    // 4 col blocks
#define NBM2 (M_TOT / BM2)    // 128 row blocks

typedef short short8 __attribute__((ext_vector_type(8)));
typedef float f32x4 __attribute__((ext_vector_type(4)));

#define GL16(gp, lp)                                                        \
    __builtin_amdgcn_global_load_lds(                                       \
        (const __attribute__((address_space(1))) unsigned int*)(gp),        \
        (__attribute__((address_space(3))) unsigned int*)(lp), 16, 0, 0)

#define BARRIER() __builtin_amdgcn_s_barrier()
// FINAL (R10/R13, session best, reproduced 204.7/204.6/204.6 µs):
// asm counted waits, AWRITE in ph1/ph3 tail behind a single sched_barrier.
// Probed and rejected: pinned-issue+lgkmcnt2 (R11 null), builtin waits
// (R12 null), 2-blocks/CU 128x256 BK=32 (R14 -14%), merged 4-phase
// (R16 -7%). Structural constraint: the fused A-path (fp32 load -> cvt_pk
// -> swizzled ds_write) serial chain can't be hidden further at HIP source
// level in a 2-wave/SIMD barrier-locked schedule; un-fusing costs a larger
// 60 µs concat BW toll (R5: 222 µs total).
#define SCHEDB()  __builtin_amdgcn_sched_barrier(0)
#define LGKM0()   asm volatile("s_waitcnt lgkmcnt(0)" ::: "memory")
#define VMCNT4()  asm volatile("s_waitcnt vmcnt(4)" ::: "memory")
#define VMCNT12() asm volatile("s_waitcnt vmcnt(12)" ::: "memory")
#define VMCNT0()  asm volatile("s_waitcnt vmcnt(0)" ::: "memory")

// HW packed f32->bf16 (RNE), 1 inst / 2 elems (T12 recipe).
static __device__ __forceinline__ short8 pack8(float4 x, float4 y) {
    unsigned w0, w1, w2, w3;
    asm("v_cvt_pk_bf16_f32 %0, %1, %2" : "=v"(w0) : "v"(x.x), "v"(x.y));
    asm("v_cvt_pk_bf16_f32 %0, %1, %2" : "=v"(w1) : "v"(x.z), "v"(x.w));
    asm("v_cvt_pk_bf16_f32 %0, %1, %2" : "=v"(w2) : "v"(y.x), "v"(y.y));
    asm("v_cvt_pk_bf16_f32 %0, %1, %2" : "=v"(w3) : "v"(y.z), "v"(y.w));
    int4 q{(int)w0, (int)w1, (int)w2, (int)w3};
    return __builtin_bit_cast(short8, q);
}

// tanh(x) = 1 - 2/(e^{2x}+1); ~1e-6 abs err, exact saturation.
static __device__ __forceinline__ float fast_tanh(float x) {
    float e = __expf(2.0f * x);
    return 1.0f - 2.0f * __builtin_amdgcn_rcpf(e + 1.0f);
}

// ---------------------------------------------------------------------------
// Kernel 1: weight concat + fp32->bf16 only (4 MB): Wb[o] = [Wk[o] | Wq[o]]
// ---------------------------------------------------------------------------
__global__ __launch_bounds__(256) void conv_w(
    const float* __restrict__ Wq, const float* __restrict__ Wk,
    unsigned short* __restrict__ Wb)
{
    int idx = blockIdx.x * 256 + threadIdx.x;
    int e0 = idx * 8;
    int o  = e0 >> 11;
    int kk = e0 & 2047;
    const float* src = (kk < H_SZ) ? (Wk + (size_t)o * H_SZ + kk)
                                   : (Wq + (size_t)o * H_SZ + (kk - H_SZ));
    float4 x = ((const float4*)src)[0];
    float4 y = ((const float4*)src)[1];
    *(short8*)(Wb + e0) = pack8(x, y);
}

// ---------------------------------------------------------------------------
// Kernel 2: 256x256x64 8-phase score GEMM with FUSED fp32->bf16 A-staging
//   (R10/R13 structure — session best, FINAL).
//   Per tile u (buf = parity):
//    ph1: LDA(ks0,mh0)+LDB0+ALOAD(rA0,kh0,u+2); BAR; LGKM0; MFMA;
//         SCHEDB; AWRITE(rA1 -> (1-buf).kh1); BAR;
//    ph2: LDA(ks0,mh1)+STAGE_B(Kh1,u+1); BAR; LGKM0; MFMA; VMCNT12; BAR;
//    ph3: LDA(ks1,mh0)+LDB1+ALOAD(rA1,kh1,u+2); BAR; LGKM0; MFMA;
//         SCHEDB; AWRITE(rA0 -> buf.kh0); BAR;
//    ph4: LDA(ks1,mh1)+STAGE_B(Kh0,u+2); BAR; LGKM0; MFMA; VMCNT12; BAR;
//   VMCNT12 FIFO-exact (VMEM stream per tile: 4A/2B/4A/2B). Tail ds_writes
//   published by the next phase's LGKM0 + barrier, >=2 barriers pre-consumer.
// ---------------------------------------------------------------------------
__global__ __launch_bounds__(512, 2) void score_gemm_8ph(
    const float* __restrict__ keyg,          // key_t  [M][1024] fp32 (k<1024)
    const float* __restrict__ qryg,          // query  [M][1024] fp32 (k>=1024)
    const unsigned short* __restrict__ Wb,   // [1024][2048] bf16
    const float* __restrict__ bias,
    const float* __restrict__ wscore,
    float* __restrict__ spart)               // [M][4]
{
    extern __shared__ char smem[];           // 128 KB dynamic
    char* Albase = smem;                     // A: 64 KB
    char* Blbase = smem + 65536;             // B: 64 KB

    const int t    = threadIdx.x;
    const int lane = t & 63;
    const int wid  = t >> 6;                 // 0..7
    const int wr   = wid >> 2;               // 0..1 (WARPS_M=2, 128 rows each)
    const int wc   = wid & 3;                // 0..3 (WARPS_N=4, 64 cols each)

    // XCD-aware remap: 512 blocks = 8 xcd * 16 bm * 4 bn (bn innermost)
    const int id  = blockIdx.x;
    const int xcd = id & 7;
    const int j   = id >> 3;                 // 0..63
    const int bn  = j & 3;
    const int bm  = xcd * 16 + (j >> 2);
    const int r0  = bm * BM2;
    const int c0  = bn * BN2;

    // ---- B staging per-lane global offsets (pre-swizzled source) ----
    const int srow = lane >> 2;
    const int scol = ((lane & 3) * 8) ^ ((lane >= 32) ? 16 : 0);
    const size_t gB0 = (size_t)(c0 + (wid)     * 16 + srow) * KD + scol;
    const size_t gB1 = (size_t)(c0 + (8 + wid) * 16 + srow) * KD + scol;

    // ---- frag ds_read addressing (swizzled) ----
    const int fr  = lane & 15;               // row within subtile / C-col
    const int fk8 = (lane >> 4) * 8;         // k-offset within 32-k step
    const int subbyte = (fr * 64 + fk8 * 2) ^ ((fr & 8) << 2);  // ^32 if fr>=8
    const char* aL = Albase + wr * 8192 + subbyte;   // + rsub*1024 immediates
    const char* bL = Blbase + wc * 4096 + subbyte;

    // A reg-staging addressing: thread covers subtiles {wid, 8+wid} of a
    // 256x32 K-half; per subtile: row 16s+(lane>>2), cols (lane&3)*8 .. +8.
    const int arow0 = r0 + wid * 16 + (lane >> 2);
    const int arow1 = r0 + (8 + wid) * 16 + (lane >> 2);
    const int acsub = (lane & 3) * 8;
    // swizzled ds_write target chunk within subtile
    const int awbyte = (lane * 16) ^ (lane & 32);

#define ALOAD(rr, khalf, kt_) do {                                           \
    int koff = (((kt_) & 31) * 64) + (khalf) * 32 + acsub;                   \
    const float* base_ = (koff < H_SZ) ? (keyg + koff)                       \
                                       : (qryg + (koff - H_SZ));             \
    const float* p0_ = base_ + (size_t)arow0 * H_SZ;                         \
    const float* p1_ = base_ + (size_t)arow1 * H_SZ;                         \
    rr[0] = ((const float4*)p0_)[0]; rr[1] = ((const float4*)p0_)[1];        \
    rr[2] = ((const float4*)p1_)[0]; rr[3] = ((const float4*)p1_)[1];        \
} while (0)
#define AWRITE(rr, buf, khalf) do {                                          \
    char* d_ = Albase + (((buf)*2 + (khalf))*16 + wid)*1024 + awbyte;        \
    *(short8*)d_            = pack8(rr[0], rr[1]);                           \
    *(short8*)(d_ + 8*1024) = pack8(rr[2], rr[3]);                           \
} while (0)
#define STAGE_B(buf, khalf, kt_) do {                                        \
    int kpos = (((kt_) & 31) * 64) + (khalf) * 32;                           \
    GL16(Wb + gB0 + kpos, Blbase + (((buf)*2 + (khalf))*16 + wid)*1024);     \
    GL16(Wb + gB1 + kpos, Blbase + (((buf)*2 + (khalf))*16 + 8 + wid)*1024); \
} while (0)

    float4 rA0[4], rA1[4];
    short8 a_f[4], b_f0[4], b_f1[4];
    f32x4 acc[8][4] = {};

#define LDA4(buf, ks, mh) do { _Pragma("unroll")                             \
    for (int m = 0; m < 4; ++m)                                              \
        a_f[m] = *(const short8*)(aL +                                       \
            (((buf)*2 + (ks))*16 + (mh)*4 + m) * 1024); } while (0)
#define LDB4(dst, buf, ks) do { _Pragma("unroll")                            \
    for (int n = 0; n < 4; ++n)                                              \
        dst[n] = *(const short8*)(bL +                                       \
            (((buf)*2 + (ks))*16 + n) * 1024); } while (0)
#define MM16(bff, mh) do {                                                   \
    __builtin_amdgcn_s_setprio(1);                                           \
    _Pragma("unroll")                                                        \
    for (int m = 0; m < 4; ++m) { _Pragma("unroll")                          \
        for (int n = 0; n < 4; ++n)                                          \
            acc[(mh)*4 + m][n] = __builtin_amdgcn_mfma_f32_16x16x32_bf16(    \
                a_f[m], bff[n], acc[(mh)*4 + m][n], 0, 0, 0); }              \
    __builtin_amdgcn_s_setprio(0); } while (0)

#define TILE(buf, u) do {                                                    \
    LDA4(buf, 0, 0); LDB4(b_f0, buf, 0); ALOAD(rA0, 0, (u)+2);               \
    BARRIER(); LGKM0(); MM16(b_f0, 0);                                       \
    SCHEDB(); AWRITE(rA1, 1-(buf), 1); BARRIER();                            \
    LDA4(buf, 0, 1); STAGE_B(1-(buf), 1, (u)+1);                             \
    BARRIER(); LGKM0(); MM16(b_f0, 1); VMCNT12(); BARRIER();                 \
    LDA4(buf, 1, 0); LDB4(b_f1, buf, 1); ALOAD(rA1, 1, (u)+2);               \
    BARRIER(); LGKM0(); MM16(b_f1, 0);                                       \
    SCHEDB(); AWRITE(rA0, buf, 0); BARRIER();                                \
    LDA4(buf, 1, 1); STAGE_B(buf, 0, (u)+2);                                 \
    BARRIER(); LGKM0(); MM16(b_f1, 1); VMCNT12(); BARRIER();                 \
} while (0)

    // ---- prologue: LDS gets T0 (A+B, both halves) + T1 Kh0 (A+B);
    //      rA1 left holding T1 Kh1 (in flight into the loop).
    STAGE_B(0, 0, 0); STAGE_B(0, 1, 0); STAGE_B(1, 0, 1);
    ALOAD(rA0, 0, 0); ALOAD(rA1, 1, 0);
    AWRITE(rA0, 0, 0); AWRITE(rA1, 0, 1);    // compiler waits rA0/rA1
    ALOAD(rA0, 0, 1);  AWRITE(rA0, 1, 0);    // T1 Kh0
    ALOAD(rA1, 1, 1);                        // T1 Kh1 (4 newest VMEM)
    VMCNT4();                                // drain all but rA1's 4 loads
    LGKM0();                                 // publish prologue ds_writes
    BARRIER();

    // ---- main loop: 32 K-tiles, unrolled x2 for static buffer index ----
    for (int it = 0; it < NT2; it += 2) {
        TILE(0, it);
        TILE(1, it + 1);
    }

    // drain stray wrapped prefetches before reusing LDS
    VMCNT0();
    __syncthreads();

    // ---- fused epilogue: tanh + w_score partial over this col-tile ----
    float* part = (float*)smem;              // [4][256]
    const int fg = lane >> 4;
    float wsv[4], bsv[4];
    #pragma unroll
    for (int n = 0; n < 4; ++n) {
        int cg = c0 + wc * 64 + n * 16 + fr;
        wsv[n] = wscore[cg];
        bsv[n] = bias[cg];
    }
    #pragma unroll
    for (int mm = 0; mm < 8; ++mm) {
        #pragma unroll
        for (int r = 0; r < 4; ++r) {
            float s = 0.f;
            #pragma unroll
            for (int n = 0; n < 4; ++n)
                s += wsv[n] * fast_tanh(acc[mm][n][r] + bsv[n]);
            s += __shfl_xor(s, 1, 64);
            s += __shfl_xor(s, 2, 64);
            s += __shfl_xor(s, 4, 64);
            s += __shfl_xor(s, 8, 64);
            if (fr == 0)
                part[wc * 256 + wr * 128 + mm * 16 + fg * 4 + r] = s;
        }
    }
    __syncthreads();
    if (t < 256) {
        float v = part[t] + part[256 + t] + part[512 + t] + part[768 + t];
        spart[(size_t)(r0 + t) * 4 + bn] = v;
    }

#undef ALOAD
#undef AWRITE
#undef STAGE_B
#undef LDA4
#undef LDB4
#undef MM16
#undef TILE
}

// ---------------------------------------------------------------------------
// Kernel 3: per-batch softmax over L (sums the 4 partials in fixed order)
// ---------------------------------------------------------------------------
__global__ __launch_bounds__(256) void softmax_k(
    const float* __restrict__ spart,         // [M][4]
    float* __restrict__ attn)
{
    __shared__ float sc[L_SZ];
    __shared__ float red[8];
    const int b = blockIdx.x, t = threadIdx.x;
    const int lane = t & 63, wid = t >> 6;

    float lmax = -1e30f;
    #pragma unroll
    for (int i = 0; i < 8; ++i) {
        int l = t + i * 256;
        float4 u = *(const float4*)(spart + ((size_t)b * L_SZ + l) * 4);
        float s = (u.x + u.y) + (u.z + u.w);
        sc[l] = s;
        lmax = fmaxf(lmax, s);
    }
    #pragma unroll
    for (int off = 32; off; off >>= 1) lmax = fmaxf(lmax, __shfl_xor(lmax, off, 64));
    if (lane == 0) red[wid] = lmax;
    __syncthreads();
    float bmax = fmaxf(fmaxf(red[0], red[1]), fmaxf(red[2], red[3]));

    float lsum = 0.f;
    #pragma unroll
    for (int i = 0; i < 8; ++i) {
        int l = t + i * 256;
        float e = expf(sc[l] - bmax);
        sc[l] = e;
        lsum += e;
    }
    #pragma unroll
    for (int off = 32; off; off >>= 1) lsum += __shfl_xor(lsum, off, 64);
    if (lane == 0) red[4 + wid] = lsum;
    __syncthreads();
    float inv = 1.f / (((red[4] + red[5]) + (red[6] + red[7])));

    #pragma unroll
    for (int i = 0; i < 8; ++i) {
        int l = t + i * 256;
        attn[(size_t)b * L_SZ + l] = sc[l] * inv;
    }
}

// ---------------------------------------------------------------------------
// Kernel 4: context partials  cpart[b][lc][h] = sum_{l in chunk} attn*V
// ---------------------------------------------------------------------------
__global__ __launch_bounds__(256) void ctx_part_k(
    const float* __restrict__ attn, const float* __restrict__ value,
    float* __restrict__ cpart)
{
    const int bid = blockIdx.x;              // B*4*LC = 1024 blocks
    const int b   = bid >> 6;
    const int rem = bid & 63;
    const int hc  = rem >> 4;
    const int lc  = rem & 15;
    const int h   = hc * 256 + threadIdx.x;

    const float* ap = attn + (size_t)b * L_SZ + lc * LCHUNK;
    const float* vp = value + ((size_t)b * L_SZ + lc * LCHUNK) * H_SZ + h;
    float acc = 0.f;
    #pragma unroll 4
    for (int l = 0; l < LCHUNK; ++l)
        acc += ap[l] * vp[(size_t)l * H_SZ];
    cpart[((size_t)(b * LC + lc)) * H_SZ + h] = acc;
}

// ---------------------------------------------------------------------------
// Kernel 5: reduce context partials -> d_out[0:16384]
// ---------------------------------------------------------------------------
__global__ __launch_bounds__(256) void ctx_reduce_k(
    const float* __restrict__ cpart, float* __restrict__ ctx)
{
    const int idx = blockIdx.x * 256 + threadIdx.x;
    const int b = idx >> 10, h = idx & 1023;
    float s = 0.f;
    #pragma unroll
    for (int lc = 0; lc < LC; ++lc)
        s += cpart[((size_t)(b * LC + lc)) * H_SZ + h];
    ctx[idx] = s;
}

// ---------------------------------------------------------------------------
extern "C" void kernel_launch(void* const* d_in, const int* in_sizes, int n_in,
                              void* d_out, int out_size, void* d_ws, size_t ws_size,
                              hipStream_t stream) {
    const float* query  = (const float*)d_in[0];
    const float* key_t  = (const float*)d_in[1];
    const float* value  = (const float*)d_in[2];
    const float* Wq     = (const float*)d_in[3];
    const float* Wk     = (const float*)d_in[4];
    const float* bias   = (const float*)d_in[5];
    const float* wscore = (const float*)d_in[6];

    float* out      = (float*)d_out;
    float* ctx_out  = out;                    // [16][1024] context
    float* attn_out = out + B_SZ * H_SZ;      // [16][2048] attn

    char* ws = (char*)d_ws;
    unsigned short* Wb = (unsigned short*)ws;                        // 4 MB
    float* spart = (float*)(ws + 4ull * 1024 * 1024);                // 512 KB [M][4]
    float* cpart = (float*)(ws + 5ull * 1024 * 1024);                // 1 MB

    (void)hipFuncSetAttribute((const void*)score_gemm_8ph,
                              hipFuncAttributeMaxDynamicSharedMemorySize, 131072);

    conv_w<<<1024, 256, 0, stream>>>(Wq, Wk, Wb);

    score_gemm_8ph<<<NBM2 * NBN2, 512, 131072, stream>>>(
        key_t, query, Wb, bias, wscore, spart);

    softmax_k<<<B_SZ, 256, 0, stream>>>(spart, attn_out);
    ctx_part_k<<<B_SZ * 4 * LC, 256, 0, stream>>>(attn_out, value, cpart);
    ctx_reduce_k<<<(B_SZ * H_SZ) / 256, 256, 0, stream>>>(cpart, ctx_out);
}